// Round 1
// baseline (343.518 us; speedup 1.0000x reference)
//
#include <hip/hip_runtime.h>
#include <math.h>

#define EPS_GS 1e-8f
#define RAD2DEG 57.29577951308232f

__device__ __forceinline__ float clip10(float x) {
    // ternary form preserves NaN (matches jnp.clip NaN propagation)
    x = x < -10.f ? -10.f : x;
    x = x >  10.f ?  10.f : x;
    return x;
}

// v: 3x3 row-major (clipped). Columns: c0=(v0,v3,v6), c1=(v1,v4,v7), c2=(v2,v5,v8).
// R: row-major rotation, columns e1,e2,e3 (e3 sign-fixed by det).
__device__ __forceinline__ void gs_rotmat(const float* v, float* R) {
    float c0x = v[0], c0y = v[3], c0z = v[6];
    float c1x = v[1], c1y = v[4], c1z = v[7];
    float c2x = v[2], c2y = v[5], c2z = v[8];

    float n1   = sqrtf(c0x*c0x + c0y*c0y + c0z*c0z);
    float inv1 = 1.f / (n1 + EPS_GS);
    float e1x = c0x*inv1, e1y = c0y*inv1, e1z = c0z*inv1;

    float d   = e1x*c1x + e1y*c1y + e1z*c1z;
    float u2x = c1x - d*e1x, u2y = c1y - d*e1y, u2z = c1z - d*e1z;
    float n2   = sqrtf(u2x*u2x + u2y*u2y + u2z*u2z);
    float inv2 = 1.f / (n2 + EPS_GS);
    float e2x = u2x*inv2, e2y = u2y*inv2, e2z = u2z*inv2;

    float d1 = e1x*c2x + e1y*c2y + e1z*c2z;
    float d2 = e2x*c2x + e2y*c2y + e2z*c2z;
    float u3x = c2x - d1*e1x - d2*e2x;
    float u3y = c2y - d1*e1y - d2*e2y;
    float u3z = c2z - d1*e1z - d2*e2z;
    float n3   = sqrtf(u3x*u3x + u3y*u3y + u3z*u3z);
    float inv3 = 1.f / (n3 + EPS_GS);
    float e3x = u3x*inv3, e3y = u3y*inv3, e3z = u3z*inv3;

    // det(Q), Q columns e1,e2,e3 == e1 . (e2 x e3)
    float det = e1x*(e2y*e3z - e2z*e3y)
              - e1y*(e2x*e3z - e2z*e3x)
              + e1z*(e2x*e3y - e2y*e3x);
    if (det < 0.f) { e3x = -e3x; e3y = -e3y; e3z = -e3z; } // NaN<0 false -> keep (matches where)

    R[0] = e1x; R[1] = e2x; R[2] = e3x;
    R[3] = e1y; R[4] = e2y; R[5] = e3y;
    R[6] = e1z; R[7] = e2z; R[8] = e3z;
}

// pr/tg: raw (unclipped) 9 floats. Accumulates the per-rotation weighted total
// and the fallback sum.
__device__ __forceinline__ void accum_rot(const float* pr, const float* tg,
                                          float& lt, float& lf) {
    float pc[9], tc[9];
    #pragma unroll
    for (int m = 0; m < 9; ++m) { pc[m] = clip10(pr[m]); tc[m] = clip10(tg[m]); }

    float Rp[9], Rt[9];
    gs_rotmat(pc, Rp);
    gs_rotmat(tc, Rt);

    float chord = 0.f, tr = 0.f;
    #pragma unroll
    for (int m = 0; m < 9; ++m) {
        float d = Rp[m] - Rt[m];
        chord = fmaf(d, d, chord);
        tr    = fmaf(Rp[m], Rt[m], tr);
    }

    // clips via ternary to preserve NaN -> acos NaN -> 180 path
    const float trLo = -3.0f + 1e-6f, trHi = 3.0f - 1e-6f;
    tr = tr < trLo ? trLo : (tr > trHi ? trHi : tr);
    float ca = (tr - 1.f) * 0.5f;
    const float cLo = -1.0f + 1e-7f, cHi = 1.0f - 1e-7f;
    ca = ca < cLo ? cLo : (ca > cHi ? cHi : ca);
    float ang = acosf(ca) * RAD2DEG;
    if (ang != ang) ang = 180.f;

    // orthogonality: AtA[i][j] = col_i . col_j of clipped pred matrix
    float o = 0.f;
    #pragma unroll
    for (int i = 0; i < 3; ++i) {
        #pragma unroll
        for (int j = 0; j < 3; ++j) {
            float s = pc[i]*pc[j] + pc[3+i]*pc[3+j] + pc[6+i]*pc[6+j];
            s -= (i == j) ? 1.f : 0.f;
            o = fmaf(s, s, o);
        }
    }

    float l2 = 0.f, fb = 0.f;
    #pragma unroll
    for (int m = 0; m < 9; ++m) {
        l2 = fmaf(pc[m], pc[m], l2);
        float d = pc[m] - tg[m];   // fallback uses UNclipped target
        fb = fmaf(d, d, fb);
    }

    lt += chord + 0.1f*ang + 0.01f*o + (1e-4f/9.f)*l2;
    lf += fb;
}

__global__ __launch_bounds__(256)
void rot_loss_kernel(const float* __restrict__ pred, const float* __restrict__ targ,
                     double* __restrict__ acc, int B) {
    const int g    = blockIdx.x * blockDim.x + threadIdx.x; // group of 4 rotations
    const int base = g * 4;

    float lt = 0.f, lf = 0.f;

    if (base + 3 < B) {
        // 4 rotations = 36 floats = 9 float4 per input; offset 144*g bytes (16B aligned)
        const float4* p4 = reinterpret_cast<const float4*>(pred) + (size_t)g * 9;
        const float4* t4 = reinterpret_cast<const float4*>(targ) + (size_t)g * 9;
        float a[36], b[36];
        #pragma unroll
        for (int j = 0; j < 9; ++j) {
            float4 x = p4[j];
            a[4*j+0] = x.x; a[4*j+1] = x.y; a[4*j+2] = x.z; a[4*j+3] = x.w;
            float4 y = t4[j];
            b[4*j+0] = y.x; b[4*j+1] = y.y; b[4*j+2] = y.z; b[4*j+3] = y.w;
        }
        #pragma unroll
        for (int k = 0; k < 4; ++k) accum_rot(&a[9*k], &b[9*k], lt, lf);
    } else if (base < B) {
        for (int r = base; r < B; ++r) {
            float a1[9], b1[9];
            for (int m = 0; m < 9; ++m) { a1[m] = pred[(size_t)r*9 + m]; b1[m] = targ[(size_t)r*9 + m]; }
            accum_rot(a1, b1, lt, lf);
        }
    }

    // wave-64 reduce
    #pragma unroll
    for (int off = 32; off > 0; off >>= 1) {
        lt += __shfl_down(lt, off, 64);
        lf += __shfl_down(lf, off, 64);
    }
    __shared__ float st[4], sf[4];
    const int lane = threadIdx.x & 63;
    const int wid  = threadIdx.x >> 6;
    if (lane == 0) { st[wid] = lt; sf[wid] = lf; }
    __syncthreads();
    if (threadIdx.x == 0) {
        float bt = st[0] + st[1] + st[2] + st[3];
        float bf = sf[0] + sf[1] + sf[2] + sf[3];
        unsafeAtomicAdd(&acc[0], (double)bt);  // HW global_atomic_add_f64
        unsafeAtomicAdd(&acc[1], (double)bf);
    }
}

__global__ void finalize_kernel(const double* __restrict__ acc,
                                float* __restrict__ out, int B) {
    if (threadIdx.x == 0 && blockIdx.x == 0) {
        double total = acc[0] / (double)B;
        double fb    = acc[1] / (9.0 * (double)B);
        out[0] = isnan(total) ? (float)fb : (float)total;
    }
}

extern "C" void kernel_launch(void* const* d_in, const int* in_sizes, int n_in,
                              void* d_out, int out_size, void* d_ws, size_t ws_size,
                              hipStream_t stream) {
    const float* pred = (const float*)d_in[0];
    const float* targ = (const float*)d_in[1];
    const int n = in_sizes[0];
    const int B = n / 9;

    double* acc = (double*)d_ws;
    hipMemsetAsync(d_ws, 0, 2 * sizeof(double), stream); // ws is re-poisoned to 0xAA each call

    const int ngroups = (B + 3) / 4;
    const int threads = 256;
    const int blocks  = (ngroups + threads - 1) / threads;
    rot_loss_kernel<<<blocks, threads, 0, stream>>>(pred, targ, acc, B);
    finalize_kernel<<<1, 64, 0, stream>>>(acc, (float*)d_out, B);
}

// Round 2
// 332.270 us; speedup vs baseline: 1.0339x; 1.0339x over previous
//
#include <hip/hip_runtime.h>
#include <math.h>

#define EPS_GS 1e-8f
#define RAD2DEG 57.29577951308232f
#define PI_F 3.14159265358979f

__device__ __forceinline__ float clip10(float x) {
    // ternary form preserves NaN (matches jnp.clip NaN propagation)
    x = x < -10.f ? -10.f : x;
    x = x >  10.f ?  10.f : x;
    return x;
}

// v_sqrt_f32 / v_rcp_f32 — ~1 ulp, single-instruction
__device__ __forceinline__ float fsqrt(float x) { return __builtin_amdgcn_sqrtf(x); }
__device__ __forceinline__ float frcp(float x)  { return __builtin_amdgcn_rcpf(x); }

// Abramowitz-Stegun 4.4.45: max error 6.76e-5 rad on [-1,1]
__device__ __forceinline__ float fast_acos(float x) {
    float ax = fabsf(x);
    float p = fmaf(ax, -0.0187293f, 0.0742610f);
    p = fmaf(ax, p, -0.2121144f);
    p = fmaf(ax, p, 1.5707288f);
    float pos = fsqrt(1.f - ax) * p;
    return x >= 0.f ? pos : PI_F - pos;
}

// v: 3x3 row-major (clipped). Columns: c0=(v0,v3,v6), c1=(v1,v4,v7), c2=(v2,v5,v8).
// R: row-major rotation, columns e1,e2,e3 (e3 sign-fixed by det).
__device__ __forceinline__ void gs_rotmat(const float* v, float* R) {
    float c0x = v[0], c0y = v[3], c0z = v[6];
    float c1x = v[1], c1y = v[4], c1z = v[7];
    float c2x = v[2], c2y = v[5], c2z = v[8];

    float s1 = fmaf(c0x, c0x, fmaf(c0y, c0y, c0z*c0z));
    float inv1 = frcp(fsqrt(s1) + EPS_GS);
    float e1x = c0x*inv1, e1y = c0y*inv1, e1z = c0z*inv1;

    float d = fmaf(e1x, c1x, fmaf(e1y, c1y, e1z*c1z));
    float u2x = fmaf(-d, e1x, c1x), u2y = fmaf(-d, e1y, c1y), u2z = fmaf(-d, e1z, c1z);
    float s2 = fmaf(u2x, u2x, fmaf(u2y, u2y, u2z*u2z));
    float inv2 = frcp(fsqrt(s2) + EPS_GS);
    float e2x = u2x*inv2, e2y = u2y*inv2, e2z = u2z*inv2;

    float d1 = fmaf(e1x, c2x, fmaf(e1y, c2y, e1z*c2z));
    float d2 = fmaf(e2x, c2x, fmaf(e2y, c2y, e2z*c2z));
    float u3x = fmaf(-d1, e1x, fmaf(-d2, e2x, c2x));
    float u3y = fmaf(-d1, e1y, fmaf(-d2, e2y, c2y));
    float u3z = fmaf(-d1, e1z, fmaf(-d2, e2z, c2z));
    float s3 = fmaf(u3x, u3x, fmaf(u3y, u3y, u3z*u3z));
    float inv3 = frcp(fsqrt(s3) + EPS_GS);
    float e3x = u3x*inv3, e3y = u3y*inv3, e3z = u3z*inv3;

    // det(Q) = e1 . (e2 x e3)
    float cxx = e2y*e3z - e2z*e3y;
    float cxy = e2z*e3x - e2x*e3z;
    float cxz = e2x*e3y - e2y*e3x;
    float det = fmaf(e1x, cxx, fmaf(e1y, cxy, e1z*cxz));
    if (det < 0.f) { e3x = -e3x; e3y = -e3y; e3z = -e3z; } // NaN<0 false -> keep

    R[0] = e1x; R[1] = e2x; R[2] = e3x;
    R[3] = e1y; R[4] = e2y; R[5] = e3y;
    R[6] = e1z; R[7] = e2z; R[8] = e3z;
}

__device__ __forceinline__ void accum_rot(const float* pr, const float* tg,
                                          float& lt, float& lf) {
    float pc[9], tc[9];
    #pragma unroll
    for (int m = 0; m < 9; ++m) { pc[m] = clip10(pr[m]); tc[m] = clip10(tg[m]); }

    float Rp[9], Rt[9];
    gs_rotmat(pc, Rp);
    gs_rotmat(tc, Rt);

    float chord = 0.f, tr = 0.f;
    #pragma unroll
    for (int m = 0; m < 9; ++m) {
        float d = Rp[m] - Rt[m];
        chord = fmaf(d, d, chord);
        tr    = fmaf(Rp[m], Rt[m], tr);
    }

    const float trLo = -3.0f + 1e-6f, trHi = 3.0f - 1e-6f;
    tr = tr < trLo ? trLo : (tr > trHi ? trHi : tr);
    float ca = (tr - 1.f) * 0.5f;
    const float cLo = -1.0f + 1e-7f, cHi = 1.0f - 1e-7f;
    ca = ca < cLo ? cLo : (ca > cHi ? cHi : ca);
    float ang = fast_acos(ca) * RAD2DEG;
    if (ang != ang) ang = 180.f;

    // orthogonality: AtA[i][j] = col_i . col_j of clipped pred matrix
    float o = 0.f;
    #pragma unroll
    for (int i = 0; i < 3; ++i) {
        #pragma unroll
        for (int j = 0; j < 3; ++j) {
            float s = fmaf(pc[i], pc[j], fmaf(pc[3+i], pc[3+j], pc[6+i]*pc[6+j]));
            s -= (i == j) ? 1.f : 0.f;
            o = fmaf(s, s, o);
        }
    }

    float l2 = 0.f, fb = 0.f;
    #pragma unroll
    for (int m = 0; m < 9; ++m) {
        l2 = fmaf(pc[m], pc[m], l2);
        float d = pc[m] - tg[m];   // fallback uses UNclipped target
        fb = fmaf(d, d, fb);
    }

    lt += fmaf(0.1f, ang, chord) + fmaf(0.01f, o, (1e-4f/9.f)*l2);
    lf += fb;
}

__global__ __launch_bounds__(256)
void rot_loss_kernel(const float* __restrict__ pred, const float* __restrict__ targ,
                     double* __restrict__ acc, int B) {
    const int g    = blockIdx.x * blockDim.x + threadIdx.x; // group of 4 rotations
    const int base = g * 4;

    float lt = 0.f, lf = 0.f;

    if (base + 3 < B) {
        const float4* p4 = reinterpret_cast<const float4*>(pred) + (size_t)g * 9;
        const float4* t4 = reinterpret_cast<const float4*>(targ) + (size_t)g * 9;
        // batch all loads first: 18 outstanding dwordx4 -> max MLP
        float4 pv[9], tv[9];
        #pragma unroll
        for (int j = 0; j < 9; ++j) pv[j] = p4[j];
        #pragma unroll
        for (int j = 0; j < 9; ++j) tv[j] = t4[j];
        float a[36], b[36];
        #pragma unroll
        for (int j = 0; j < 9; ++j) {
            a[4*j+0] = pv[j].x; a[4*j+1] = pv[j].y; a[4*j+2] = pv[j].z; a[4*j+3] = pv[j].w;
            b[4*j+0] = tv[j].x; b[4*j+1] = tv[j].y; b[4*j+2] = tv[j].z; b[4*j+3] = tv[j].w;
        }
        #pragma unroll
        for (int k = 0; k < 4; ++k) accum_rot(&a[9*k], &b[9*k], lt, lf);
    } else if (base < B) {
        for (int r = base; r < B; ++r) {
            float a1[9], b1[9];
            for (int m = 0; m < 9; ++m) { a1[m] = pred[(size_t)r*9 + m]; b1[m] = targ[(size_t)r*9 + m]; }
            accum_rot(a1, b1, lt, lf);
        }
    }

    // wave-64 reduce
    #pragma unroll
    for (int off = 32; off > 0; off >>= 1) {
        lt += __shfl_down(lt, off, 64);
        lf += __shfl_down(lf, off, 64);
    }
    __shared__ float st[4], sf[4];
    const int lane = threadIdx.x & 63;
    const int wid  = threadIdx.x >> 6;
    if (lane == 0) { st[wid] = lt; sf[wid] = lf; }
    __syncthreads();
    if (threadIdx.x == 0) {
        float bt = st[0] + st[1] + st[2] + st[3];
        float bf = sf[0] + sf[1] + sf[2] + sf[3];
        unsafeAtomicAdd(&acc[0], (double)bt);  // HW global_atomic_add_f64
        unsafeAtomicAdd(&acc[1], (double)bf);
    }
}

__global__ void finalize_kernel(const double* __restrict__ acc,
                                float* __restrict__ out, int B) {
    if (threadIdx.x == 0 && blockIdx.x == 0) {
        double total = acc[0] / (double)B;
        double fb    = acc[1] / (9.0 * (double)B);
        out[0] = isnan(total) ? (float)fb : (float)total;
    }
}

extern "C" void kernel_launch(void* const* d_in, const int* in_sizes, int n_in,
                              void* d_out, int out_size, void* d_ws, size_t ws_size,
                              hipStream_t stream) {
    const float* pred = (const float*)d_in[0];
    const float* targ = (const float*)d_in[1];
    const int n = in_sizes[0];
    const int B = n / 9;

    double* acc = (double*)d_ws;
    hipMemsetAsync(d_ws, 0, 2 * sizeof(double), stream);

    const int ngroups = (B + 3) / 4;
    const int threads = 256;
    const int blocks  = (ngroups + threads - 1) / threads;
    rot_loss_kernel<<<blocks, threads, 0, stream>>>(pred, targ, acc, B);
    finalize_kernel<<<1, 64, 0, stream>>>(acc, (float*)d_out, B);
}